// Round 11
// baseline (137.268 us; speedup 1.0000x reference)
//
#include <hip/hip_runtime.h>
#include <hip/hip_bf16.h>

// Problem constants
#define N_NODES 8
#define N_EDGES 64
#define CO 64
#define OH 128
#define OW 128
#define FEAT 1024
#define BN_EPS 1e-5f

// Workspace layout (bytes):
//   partial @ 0        : 16 rt x 36 pairs x 64 c fp32 = 147,456 (pad 151,552)
//   xpad    @ 151552   : 8*3*262*264 bf16 = 3,320,064
//   wb2     @ 3471616  : 24*128*8 bf16 = 49,152
//   A2      @ 3520768  : 16,777,216
//   B2      @ 20297984 : 16,777,216
#define OFF_PARTIAL 0
#define OFF_XPAD    151552
#define OFF_WB      3471616
#define OFF_A       3520768
#define OFF_B       20297984

#define RS_W 136        // conv raw row stride in u32 words
#define XROW 132        // xpad row stride in u32 words

typedef short bf16x8 __attribute__((ext_vector_type(8)));
typedef float f32x4  __attribute__((ext_vector_type(4)));

__device__ __forceinline__ unsigned short f2bf(float f) {   // RNE f32->bf16
    unsigned u = __float_as_uint(f);
    u += 0x7fffu + ((u >> 16) & 1u);
    return (unsigned short)(u >> 16);
}
__device__ __forceinline__ float blo(unsigned u) { return __uint_as_float(u << 16); }
__device__ __forceinline__ float bhi(unsigned u) { return __uint_as_float(u & 0xffff0000u); }

// ---------------------------------------------------------------------------
// K0: prep — pad+convert image to bf16 once + weight repack (unchanged R10).
__global__ __launch_bounds__(256) void prep_kernel(
        const float* __restrict__ x, const float* __restrict__ w,
        const float* __restrict__ gamma, const float* __restrict__ var,
        unsigned* __restrict__ xpad, unsigned short* __restrict__ wb2) {
    int idx = blockIdx.x * 256 + threadIdx.x;
    if (idx < 8 * 3 * 262 * XROW) {
        int u   = idx % XROW;
        int r   = idx / XROW;
        int iyp = r % 262;
        int nc  = r / 262;
        int iy  = iyp - 3;
        unsigned val = 0u;
        if ((unsigned)iy < 256u) {
            int c0 = 2 * u - 3;
            const float* row = x + (size_t)nc * 65536 + iy * 256;
            float f0 = ((unsigned)c0 < 256u) ? row[c0] : 0.f;
            float f1 = ((unsigned)(c0 + 1) < 256u) ? row[c0 + 1] : 0.f;
            val = (unsigned)f2bf(f0) | ((unsigned)f2bf(f1) << 16);
        }
        xpad[idx] = val;
    }
    if (idx < 2 * 64 * 192) {
        int tp = idx % 192;
        int c  = (idx / 192) & 63;
        int h  = idx / (192 * 64);
        int rr = tp >> 3, kx = tp & 7;
        float val = 0.f;
        if (rr < 21 && kx < 7) {
            int ci = rr / 7, ky = rr % 7;
            float sc = gamma[c] * rsqrtf(var[c] + BN_EPS);
            val = w[((c * 6 + h * 3 + ci) * 7 + ky) * 7 + kx] * sc;
        }
        wb2[(rr * 128 + h * 64 + c) * 8 + kx] = f2bf(val);
    }
}

// ---------------------------------------------------------------------------
// K1: MFMA conv (unchanged R10): 1024 blocks x 1024 thr, 16 waves,
// acc[2][2]=16 VGPR -> 64-VGPR class, 32 waves/CU.
__global__ __launch_bounds__(1024, 4) void conv_kernel(
        const unsigned* __restrict__ xpad, const unsigned short* __restrict__ wb2,
        const float* __restrict__ gamma, const float* __restrict__ beta,
        const float* __restrict__ mean,  const float* __restrict__ var,
        unsigned short* __restrict__ A2, unsigned short* __restrict__ B2) {
    int bx  = blockIdx.x;
    int r16 = bx & 7;                  // XCD-pinned row-group (matches pool)
    int idx = bx >> 3;
    int n   = idx >> 4;
    int oy  = (r16 << 4) + (idx & 15);
    int t   = threadIdx.x;

    __shared__ __align__(16) char smem[32768];
    unsigned* rawu = (unsigned*)smem;

    const unsigned* src = xpad + (size_t)n * (3 * 262 * XROW);
    if (t < 816) {                      // 24*34, single round
        int g  = t % 34;
        int rr = t / 34;
        uint4 v = make_uint4(0u, 0u, 0u, 0u);
        if (rr < 21 && g < 33) {
            int ci = (rr * 147) >> 10;  // rr/7 for rr<24
            int ky = rr - ci * 7;
            v = *(const uint4*)(src + (ci * 262 + 2 * oy + ky) * XROW + 4 * g);
        }
        *(uint4*)&rawu[rr * RS_W + 4 * g] = v;
    }
    __syncthreads();

    int wv = t >> 6, lane = t & 63;
    int h   = wv & 1;
    int wg  = (wv >> 1) & 3;
    int cth = wv >> 3;
    int quad = lane >> 4, m = lane & 15;

    f32x4 acc[2][2];
#pragma unroll
    for (int ctl = 0; ctl < 2; ++ctl) {
        acc[ctl][0] = (f32x4){0.f, 0.f, 0.f, 0.f};
        acc[ctl][1] = (f32x4){0.f, 0.f, 0.f, 0.f};
    }

    const bf16x8* wbv = (const bf16x8*)wb2;

#pragma unroll 2
    for (int s = 0; s < 6; ++s) {
        int rq = 4 * s + quad;
        bf16x8 afrag[2];
#pragma unroll
        for (int nt = 0; nt < 2; ++nt) {
            int ox = 32 * wg + 16 * nt + m;
            int base = rq * RS_W + ox;
            union { unsigned u[4]; bf16x8 v; } bb;
            bb.u[0] = rawu[base];     bb.u[1] = rawu[base + 1];
            bb.u[2] = rawu[base + 2]; bb.u[3] = rawu[base + 3];
            afrag[nt] = bb.v;
        }
#pragma unroll
        for (int ctl = 0; ctl < 2; ++ctl) {
            int ct = 2 * cth + ctl;
            bf16x8 wfrag = wbv[rq * 128 + h * 64 + 16 * ct + m];
#pragma unroll
            for (int nt = 0; nt < 2; ++nt)
                acc[ctl][nt] = __builtin_amdgcn_mfma_f32_16x16x32_bf16(
                                   afrag[nt], wfrag, acc[ctl][nt], 0, 0, 0);
        }
    }

    float sh[2] = {0.f, 0.f};
    if (h) {
#pragma unroll
        for (int ctl = 0; ctl < 2; ++ctl) {
            int c = 16 * (2 * cth + ctl) + m;
            float sc = gamma[c] * rsqrtf(var[c] + BN_EPS);
            sh[ctl] = beta[c] - mean[c] * sc;
        }
    }

    __syncthreads();
    unsigned short* T = (unsigned short*)smem;   // [128 chp][128 px], swizzled

#pragma unroll
    for (int ctl = 0; ctl < 2; ++ctl) {
        int chp = h * 64 + 16 * (2 * cth + ctl) + m;
        int sw  = (chp & 7) << 2;
#pragma unroll
        for (int nt = 0; nt < 2; ++nt) {
            int px0 = 32 * wg + 16 * nt + 4 * quad;
            float v0 = acc[ctl][nt][0] + sh[ctl];
            float v1 = acc[ctl][nt][1] + sh[ctl];
            float v2 = acc[ctl][nt][2] + sh[ctl];
            float v3 = acc[ctl][nt][3] + sh[ctl];
            uint2 pk;
            pk.x = (unsigned)f2bf(v0) | ((unsigned)f2bf(v1) << 16);
            pk.y = (unsigned)f2bf(v2) | ((unsigned)f2bf(v3) << 16);
            int gs = ((px0 >> 2) ^ sw);
            *(uint2*)&T[chp * 128 + gs * 4] = pk;
        }
    }
    __syncthreads();

    int row = t >> 3, slot = t & 7;
    int hh = row >> 6, ch = row & 63;
    int swr = (row & 7) << 2;
    unsigned short* dst = (hh ? B2 : A2)
                        + ((size_t)(n * CO + ch) << 14) + (oy << 7) + slot * 16;
#pragma unroll
    for (int i = 0; i < 2; ++i) {
        int g  = slot * 4 + i * 2;
        int gs = g ^ swr;
        *(uint4*)(dst + i * 8) = *(uint4*)&T[row * 128 + gs * 4];
    }
}

// ---------------------------------------------------------------------------
// K2: pool v4 — wide lanes: 8 pairs x 8 tc per wave; each lane produces
// 4 out-rows x 8 out-cols from the SAME 54 LDS reads that previously made
// 4x4 (block LDS instrs 648 -> 270). 36 pairs in 2 iters (waves 1-3 skip
// iter 2 wave-uniformly). Reads stay at the 8-way b128 bank floor.
__global__ __launch_bounds__(256, 4) void pool_kernel(
        const unsigned short* __restrict__ A2,
        const unsigned short* __restrict__ B2,
        float* __restrict__ partial) {
    int pb  = blockIdx.x;
    int xcd = pb & 7;
    int q   = pb >> 3;
    int c   = q >> 1;
    int rt  = xcd * 2 + (q & 1);
    int t   = threadIdx.x;

    __shared__ unsigned short S[2 * 8 * 9 * 128];   // plane 1152, row 128

    for (int k = t; k < 2304; k += 256) {
        int slot = k & 15;
        int r    = (k >> 4) % 9;
        int tn   = (k >> 4) / 9;
        int grow = 8 * rt - 1 + r;
        uint4 v = make_uint4(0u, 0u, 0u, 0u);
        if (grow >= 0) {
            const unsigned short* src = (tn >= 8) ? B2 : A2;
            int node = tn & 7;
            v = *(const uint4*)(src + ((size_t)(node * CO + c) << 14)
                                    + (grow << 7) + slot * 8);
        }
        *(uint4*)&S[tn * 1152 + (r << 7) + slot * 8] = v;
    }
    __syncthreads();

    int wv = t >> 6, lane = t & 63;
    int esub = lane >> 3;               // pair sub-slot 0..7
    int tc   = lane & 7;                // out cols 8tc..8tc+7 (in 16tc-1..16tc+15)

    for (int i = 0; i < 2; ++i) {
        int slot0 = 32 * i + 8 * wv;    // wave's first pair slot
        if (slot0 >= 36) continue;      // wave-uniform skip
        int sidx = slot0 + esub;
        bool valid = sidx < 36;
        int ss = valid ? sidx : 0;
        int pi = 0, rem = ss;           // unrank (pi<=pj)
        while (rem >= 8 - pi) { rem -= 8 - pi; ++pi; }
        int pj = pi + rem;
        const unsigned short* pa  = &S[pi * 1152];
        const unsigned short* pb2 = &S[(8 + pj) * 1152];

        float mx[4][8];
#pragma unroll
        for (int p = 0; p < 4; ++p)
#pragma unroll
            for (int qq = 0; qq < 8; ++qq) mx[p][qq] = 0.f;

#pragma unroll
        for (int r = 0; r < 9; ++r) {
            const unsigned short* ra = pa + (r << 7) + tc * 16;
            const unsigned short* rb = pb2 + (r << 7) + tc * 16;
            uint4 ga0 = *(const uint4*)(ra);
            uint4 ga1 = *(const uint4*)(ra + 8);
            uint4 gb0 = *(const uint4*)(rb);
            uint4 gb1 = *(const uint4*)(rb + 8);
            float ha = 0.f, hb = 0.f;
            if (tc > 0) {               // in col 16tc-1
                ha = bhi(*(const unsigned*)(ra - 2));
                hb = bhi(*(const unsigned*)(rb - 2));
            }
            float z[17];
            z[0]  = ha + hb;
            z[1]  = blo(ga0.x) + blo(gb0.x);  z[2]  = bhi(ga0.x) + bhi(gb0.x);
            z[3]  = blo(ga0.y) + blo(gb0.y);  z[4]  = bhi(ga0.y) + bhi(gb0.y);
            z[5]  = blo(ga0.z) + blo(gb0.z);  z[6]  = bhi(ga0.z) + bhi(gb0.z);
            z[7]  = blo(ga0.w) + blo(gb0.w);  z[8]  = bhi(ga0.w) + bhi(gb0.w);
            z[9]  = blo(ga1.x) + blo(gb1.x);  z[10] = bhi(ga1.x) + bhi(gb1.x);
            z[11] = blo(ga1.y) + blo(gb1.y);  z[12] = bhi(ga1.y) + bhi(gb1.y);
            z[13] = blo(ga1.z) + blo(gb1.z);  z[14] = bhi(ga1.z) + bhi(gb1.z);
            z[15] = blo(ga1.w) + blo(gb1.w);  z[16] = bhi(ga1.w) + bhi(gb1.w);
            float hwin[8];
#pragma unroll
            for (int qq = 0; qq < 8; ++qq)
                hwin[qq] = fmaxf(fmaxf(z[2 * qq], z[2 * qq + 1]), z[2 * qq + 2]);
            // input row r (global 8rt-1+r): r odd -> out row (r-1)/2;
            // r even -> out rows r/2-1 and r/2 (clamped to [0,3])
            if (r & 1) {
                int p = (r - 1) >> 1;
#pragma unroll
                for (int qq = 0; qq < 8; ++qq)
                    mx[p][qq] = fmaxf(mx[p][qq], hwin[qq]);
            } else {
                if (r >= 2) {
                    int p = (r >> 1) - 1;
#pragma unroll
                    for (int qq = 0; qq < 8; ++qq)
                        mx[p][qq] = fmaxf(mx[p][qq], hwin[qq]);
                }
                if (r <= 6) {
                    int p = r >> 1;
#pragma unroll
                    for (int qq = 0; qq < 8; ++qq)
                        mx[p][qq] = fmaxf(mx[p][qq], hwin[qq]);
                }
            }
        }

        float sum = 0.f;
#pragma unroll
        for (int p = 0; p < 4; ++p)
#pragma unroll
            for (int qq = 0; qq < 8; ++qq) sum += fmaxf(mx[p][qq], 0.f);

        sum += __shfl_down(sum, 4, 64);     // reduce over 8 tc lanes
        sum += __shfl_down(sum, 2, 64);
        sum += __shfl_down(sum, 1, 64);
        if (tc == 0 && valid)
            partial[(rt * 36 + sidx) * 64 + c] = sum;
    }
}

// ---------------------------------------------------------------------------
// K3: head (unchanged R10).
__global__ __launch_bounds__(256) void head_kernel(
        const int* __restrict__ ei, const float* __restrict__ partial,
        const float* __restrict__ fc_w,   const float* __restrict__ fc_b,
        const float* __restrict__ xyz_w,  const float* __restrict__ xyz_b,
        const float* __restrict__ wpqr_w, const float* __restrict__ wpqr_b,
        float* __restrict__ out) {
    int e = blockIdx.x;
    int t = threadIdx.x;
    int a0 = ei[e], a1 = ei[N_EDGES + e];
    int pi = min(a0, a1), pj = max(a0, a1);
    int rank = pi * 8 - ((pi * (pi + 1)) >> 1) + pj;
    __shared__ float pl[CO];
    if (t < CO) {
        float s = 0.f;
#pragma unroll
        for (int rt = 0; rt < 16; ++rt)
            s += partial[(rt * 36 + rank) * 64 + t];
        pl[t] = s * (1.f / 4096.f);
    }
    __syncthreads();

    float s[6] = {0.f, 0.f, 0.f, 0.f, 0.f, 0.f};
#pragma unroll
    for (int ff = 0; ff < 4; ++ff) {
        int f = ff * 256 + t;
        const float* wr = fc_w + f * CO;
        float d = fc_b[f];
#pragma unroll
        for (int c = 0; c < CO; ++c) d = fmaf(pl[c], wr[c], d);
        d = fmaxf(d, 0.f);
#pragma unroll
        for (int r = 0; r < 3; ++r) {
            s[r]     = fmaf(d, xyz_w[r * FEAT + f],  s[r]);
            s[3 + r] = fmaf(d, wpqr_w[r * FEAT + f], s[3 + r]);
        }
    }
#pragma unroll
    for (int r = 0; r < 6; ++r)
#pragma unroll
        for (int off = 32; off > 0; off >>= 1)
            s[r] += __shfl_down(s[r], off, 64);

    __shared__ float red[4][6];
    if ((t & 63) == 0) {
#pragma unroll
        for (int r = 0; r < 6; ++r) red[t >> 6][r] = s[r];
    }
    __syncthreads();
    if (t < 6) {
        float v = red[0][t] + red[1][t] + red[2][t] + red[3][t];
        v += (t < 3) ? xyz_b[t] : wpqr_b[t - 3];
        out[48 + e * 6 + t] = v;
        if (e < 8) out[e * 6 + t] = v;
    }
}

// ---------------------------------------------------------------------------
extern "C" void kernel_launch(void* const* d_in, const int* in_sizes, int n_in,
                              void* d_out, int out_size, void* d_ws, size_t ws_size,
                              hipStream_t stream) {
    const float* x        = (const float*)d_in[0];
    const int*   ei       = (const int*)d_in[1];
    const float* conv1_w  = (const float*)d_in[2];
    const float* bn_gamma = (const float*)d_in[3];
    const float* bn_beta  = (const float*)d_in[4];
    const float* bn_mean  = (const float*)d_in[5];
    const float* bn_var   = (const float*)d_in[6];
    const float* fc_w     = (const float*)d_in[7];
    const float* fc_b     = (const float*)d_in[8];
    const float* xyz_w    = (const float*)d_in[9];
    const float* xyz_b    = (const float*)d_in[10];
    const float* wpqr_w   = (const float*)d_in[11];
    const float* wpqr_b   = (const float*)d_in[12];
    float* out = (float*)d_out;

    char* ws = (char*)d_ws;
    float*          partial = (float*)(ws + OFF_PARTIAL);
    unsigned*       xpad    = (unsigned*)(ws + OFF_XPAD);
    unsigned short* wb2     = (unsigned short*)(ws + OFF_WB);
    unsigned short* A2      = (unsigned short*)(ws + OFF_A);
    unsigned short* B2      = (unsigned short*)(ws + OFF_B);

    int img_work = 8 * 3 * 262 * XROW;
    prep_kernel<<<(img_work + 255) / 256, 256, 0, stream>>>(
        x, conv1_w, bn_gamma, bn_var, xpad, wb2);
    conv_kernel<<<1024, 1024, 0, stream>>>(xpad, wb2, bn_gamma, bn_beta,
                                           bn_mean, bn_var, A2, B2);
    pool_kernel<<<1024, 256, 0, stream>>>(A2, B2, partial);
    head_kernel<<<64, 256, 0, stream>>>(ei, partial, fc_w, fc_b,
                                        xyz_w, xyz_b, wpqr_w, wpqr_b, out);
}

// Round 12
// 130.072 us; speedup vs baseline: 1.0553x; 1.0553x over previous
//
#include <hip/hip_runtime.h>
#include <hip/hip_bf16.h>

// Problem constants
#define N_NODES 8
#define N_EDGES 64
#define CO 64
#define OH 128
#define OW 128
#define FEAT 1024
#define BN_EPS 1e-5f

// Workspace layout (bytes):
//   partial @ 0        : 16 rt x 36 pairs x 64 c fp32 = 147,456 (pad 151,552)
//   xpad    @ 151552   : 8*3*262*264 bf16 = 3,320,064
//   wb2     @ 3471616  : 24*128*8 bf16 = 49,152
//   A2      @ 3520768  : 16,777,216
//   B2      @ 20297984 : 16,777,216
#define OFF_PARTIAL 0
#define OFF_XPAD    151552
#define OFF_WB      3471616
#define OFF_A       3520768
#define OFF_B       20297984

#define RS_W 136        // conv raw row stride in u32 words
#define XROW 132        // xpad row stride in u32 words

typedef short bf16x8 __attribute__((ext_vector_type(8)));
typedef float f32x4  __attribute__((ext_vector_type(4)));

__device__ __forceinline__ unsigned short f2bf(float f) {   // RNE f32->bf16
    unsigned u = __float_as_uint(f);
    u += 0x7fffu + ((u >> 16) & 1u);
    return (unsigned short)(u >> 16);
}
__device__ __forceinline__ float blo(unsigned u) { return __uint_as_float(u << 16); }
__device__ __forceinline__ float bhi(unsigned u) { return __uint_as_float(u & 0xffff0000u); }

// ---------------------------------------------------------------------------
// K0: prep — pad+convert image to bf16 once + weight repack.
__global__ __launch_bounds__(256) void prep_kernel(
        const float* __restrict__ x, const float* __restrict__ w,
        const float* __restrict__ gamma, const float* __restrict__ var,
        unsigned* __restrict__ xpad, unsigned short* __restrict__ wb2) {
    int idx = blockIdx.x * 256 + threadIdx.x;
    if (idx < 8 * 3 * 262 * XROW) {
        int u   = idx % XROW;
        int r   = idx / XROW;
        int iyp = r % 262;
        int nc  = r / 262;
        int iy  = iyp - 3;
        unsigned val = 0u;
        if ((unsigned)iy < 256u) {
            int c0 = 2 * u - 3;
            const float* row = x + (size_t)nc * 65536 + iy * 256;
            float f0 = ((unsigned)c0 < 256u) ? row[c0] : 0.f;
            float f1 = ((unsigned)(c0 + 1) < 256u) ? row[c0 + 1] : 0.f;
            val = (unsigned)f2bf(f0) | ((unsigned)f2bf(f1) << 16);
        }
        xpad[idx] = val;
    }
    if (idx < 2 * 64 * 192) {
        int tp = idx % 192;
        int c  = (idx / 192) & 63;
        int h  = idx / (192 * 64);
        int rr = tp >> 3, kx = tp & 7;
        float val = 0.f;
        if (rr < 21 && kx < 7) {
            int ci = rr / 7, ky = rr % 7;
            float sc = gamma[c] * rsqrtf(var[c] + BN_EPS);
            val = w[((c * 6 + h * 3 + ci) * 7 + ky) * 7 + kx] * sc;
        }
        wb2[(rr * 128 + h * 64 + c) * 8 + kx] = f2bf(val);
    }
}

// ---------------------------------------------------------------------------
// K1: MFMA conv: 1024 blocks x 1024 thr, 16 waves, acc[2][2]=16 VGPR ->
// 64-VGPR class, 32 waves/CU.
__global__ __launch_bounds__(1024, 4) void conv_kernel(
        const unsigned* __restrict__ xpad, const unsigned short* __restrict__ wb2,
        const float* __restrict__ gamma, const float* __restrict__ beta,
        const float* __restrict__ mean,  const float* __restrict__ var,
        unsigned short* __restrict__ A2, unsigned short* __restrict__ B2) {
    int bx  = blockIdx.x;
    int r16 = bx & 7;                  // XCD-pinned row-group (matches pool)
    int idx = bx >> 3;
    int n   = idx >> 4;
    int oy  = (r16 << 4) + (idx & 15);
    int t   = threadIdx.x;

    __shared__ __align__(16) char smem[32768];
    unsigned* rawu = (unsigned*)smem;

    const unsigned* src = xpad + (size_t)n * (3 * 262 * XROW);
    if (t < 816) {                      // 24*34, single round
        int g  = t % 34;
        int rr = t / 34;
        uint4 v = make_uint4(0u, 0u, 0u, 0u);
        if (rr < 21 && g < 33) {
            int ci = (rr * 147) >> 10;  // rr/7 for rr<24
            int ky = rr - ci * 7;
            v = *(const uint4*)(src + (ci * 262 + 2 * oy + ky) * XROW + 4 * g);
        }
        *(uint4*)&rawu[rr * RS_W + 4 * g] = v;
    }
    __syncthreads();

    int wv = t >> 6, lane = t & 63;
    int h   = wv & 1;
    int wg  = (wv >> 1) & 3;
    int cth = wv >> 3;
    int quad = lane >> 4, m = lane & 15;

    f32x4 acc[2][2];
#pragma unroll
    for (int ctl = 0; ctl < 2; ++ctl) {
        acc[ctl][0] = (f32x4){0.f, 0.f, 0.f, 0.f};
        acc[ctl][1] = (f32x4){0.f, 0.f, 0.f, 0.f};
    }

    const bf16x8* wbv = (const bf16x8*)wb2;

#pragma unroll 2
    for (int s = 0; s < 6; ++s) {
        int rq = 4 * s + quad;
        bf16x8 afrag[2];
#pragma unroll
        for (int nt = 0; nt < 2; ++nt) {
            int ox = 32 * wg + 16 * nt + m;
            int base = rq * RS_W + ox;
            union { unsigned u[4]; bf16x8 v; } bb;
            bb.u[0] = rawu[base];     bb.u[1] = rawu[base + 1];
            bb.u[2] = rawu[base + 2]; bb.u[3] = rawu[base + 3];
            afrag[nt] = bb.v;
        }
#pragma unroll
        for (int ctl = 0; ctl < 2; ++ctl) {
            int ct = 2 * cth + ctl;
            bf16x8 wfrag = wbv[rq * 128 + h * 64 + 16 * ct + m];
#pragma unroll
            for (int nt = 0; nt < 2; ++nt)
                acc[ctl][nt] = __builtin_amdgcn_mfma_f32_16x16x32_bf16(
                                   afrag[nt], wfrag, acc[ctl][nt], 0, 0, 0);
        }
    }

    float sh[2] = {0.f, 0.f};
    if (h) {
#pragma unroll
        for (int ctl = 0; ctl < 2; ++ctl) {
            int c = 16 * (2 * cth + ctl) + m;
            float sc = gamma[c] * rsqrtf(var[c] + BN_EPS);
            sh[ctl] = beta[c] - mean[c] * sc;
        }
    }

    __syncthreads();
    unsigned short* T = (unsigned short*)smem;   // [128 chp][128 px], swizzled

#pragma unroll
    for (int ctl = 0; ctl < 2; ++ctl) {
        int chp = h * 64 + 16 * (2 * cth + ctl) + m;
        int sw  = (chp & 7) << 2;
#pragma unroll
        for (int nt = 0; nt < 2; ++nt) {
            int px0 = 32 * wg + 16 * nt + 4 * quad;
            float v0 = acc[ctl][nt][0] + sh[ctl];
            float v1 = acc[ctl][nt][1] + sh[ctl];
            float v2 = acc[ctl][nt][2] + sh[ctl];
            float v3 = acc[ctl][nt][3] + sh[ctl];
            uint2 pk;
            pk.x = (unsigned)f2bf(v0) | ((unsigned)f2bf(v1) << 16);
            pk.y = (unsigned)f2bf(v2) | ((unsigned)f2bf(v3) << 16);
            int gs = ((px0 >> 2) ^ sw);
            *(uint2*)&T[chp * 128 + gs * 4] = pk;
        }
    }
    __syncthreads();

    int row = t >> 3, slot = t & 7;
    int hh = row >> 6, ch = row & 63;
    int swr = (row & 7) << 2;
    unsigned short* dst = (hh ? B2 : A2)
                        + ((size_t)(n * CO + ch) << 14) + (oy << 7) + slot * 16;
#pragma unroll
    for (int i = 0; i < 2; ++i) {
        int g  = slot * 4 + i * 2;
        int gs = g ^ swr;
        *(uint4*)(dst + i * 8) = *(uint4*)&T[row * 128 + gs * 4];
    }
}

// ---------------------------------------------------------------------------
// K2: pool (REVERTED to the R10 version — 16-tc lanes sit exactly at the
// 8-way b128 bank floor; R11's 8-tc wide-lane variant collapsed onto 4
// bank-quads = 16-way conflicts and regressed ~10 us).
__global__ __launch_bounds__(256, 4) void pool_kernel(
        const unsigned short* __restrict__ A2,
        const unsigned short* __restrict__ B2,
        float* __restrict__ partial) {
    int pb  = blockIdx.x;
    int xcd = pb & 7;
    int q   = pb >> 3;
    int c   = q >> 1;
    int rt  = xcd * 2 + (q & 1);
    int t   = threadIdx.x;

    __shared__ unsigned short S[2 * 8 * 9 * 128];   // plane 1152, row 128

    for (int k = t; k < 2304; k += 256) {
        int slot = k & 15;
        int r    = (k >> 4) % 9;
        int tn   = (k >> 4) / 9;
        int grow = 8 * rt - 1 + r;
        uint4 v = make_uint4(0u, 0u, 0u, 0u);
        if (grow >= 0) {
            const unsigned short* src = (tn >= 8) ? B2 : A2;
            int node = tn & 7;
            v = *(const uint4*)(src + ((size_t)(node * CO + c) << 14)
                                    + (grow << 7) + slot * 8);
        }
        *(uint4*)&S[tn * 1152 + (r << 7) + slot * 8] = v;
    }
    __syncthreads();

    int wv = t >> 6, lane = t & 63;
    int esub = lane >> 4, tc = lane & 15;

    for (int i = 0; i < 3; ++i) {
        int sidx = 12 * wv + 4 * i + esub;          // pair slot 0..47
        bool valid = sidx < 36;
        int ss = valid ? sidx : 0;
        int pi = 0, rem = ss;                        // unrank (pi<=pj)
        while (rem >= 8 - pi) { rem -= 8 - pi; ++pi; }
        int pj = pi + rem;
        const unsigned short* pa  = &S[pi * 1152];
        const unsigned short* pb2 = &S[(8 + pj) * 1152];

        float mx[4][4];
#pragma unroll
        for (int p = 0; p < 4; ++p)
#pragma unroll
            for (int qq = 0; qq < 4; ++qq) mx[p][qq] = 0.f;

#pragma unroll
        for (int r = 0; r < 9; ++r) {
            uint4 ga = *(const uint4*)(pa + (r << 7) + tc * 8);
            uint4 gb = *(const uint4*)(pb2 + (r << 7) + tc * 8);
            float ha = 0.f, hb = 0.f;
            if (tc > 0) {
                ha = bhi(*(const unsigned*)(pa + (r << 7) + tc * 8 - 2));
                hb = bhi(*(const unsigned*)(pb2 + (r << 7) + tc * 8 - 2));
            }
            float z0 = ha + hb;
            float z1 = blo(ga.x) + blo(gb.x), z2 = bhi(ga.x) + bhi(gb.x);
            float z3 = blo(ga.y) + blo(gb.y), z4 = bhi(ga.y) + bhi(gb.y);
            float z5 = blo(ga.z) + blo(gb.z), z6 = bhi(ga.z) + bhi(gb.z);
            float z7 = blo(ga.w) + blo(gb.w), z8 = bhi(ga.w) + bhi(gb.w);
            float h0 = fmaxf(fmaxf(z0, z1), z2);
            float h1 = fmaxf(fmaxf(z2, z3), z4);
            float h2 = fmaxf(fmaxf(z4, z5), z6);
            float h3 = fmaxf(fmaxf(z6, z7), z8);
            if (r & 1) {
                int p = (r - 1) >> 1;
                mx[p][0] = fmaxf(mx[p][0], h0); mx[p][1] = fmaxf(mx[p][1], h1);
                mx[p][2] = fmaxf(mx[p][2], h2); mx[p][3] = fmaxf(mx[p][3], h3);
            } else {
                if (r >= 2) {
                    int p = (r >> 1) - 1;
                    mx[p][0] = fmaxf(mx[p][0], h0); mx[p][1] = fmaxf(mx[p][1], h1);
                    mx[p][2] = fmaxf(mx[p][2], h2); mx[p][3] = fmaxf(mx[p][3], h3);
                }
                if (r <= 6) {
                    int p = r >> 1;
                    mx[p][0] = fmaxf(mx[p][0], h0); mx[p][1] = fmaxf(mx[p][1], h1);
                    mx[p][2] = fmaxf(mx[p][2], h2); mx[p][3] = fmaxf(mx[p][3], h3);
                }
            }
        }

        float sum = 0.f;
#pragma unroll
        for (int p = 0; p < 4; ++p)
#pragma unroll
            for (int qq = 0; qq < 4; ++qq) sum += fmaxf(mx[p][qq], 0.f);

        sum += __shfl_down(sum, 8, 64);
        sum += __shfl_down(sum, 4, 64);
        sum += __shfl_down(sum, 2, 64);
        sum += __shfl_down(sum, 1, 64);
        if (tc == 0 && valid)
            partial[(rt * 36 + sidx) * 64 + c] = sum;
    }
}

// ---------------------------------------------------------------------------
// K3: head (unchanged).
__global__ __launch_bounds__(256) void head_kernel(
        const int* __restrict__ ei, const float* __restrict__ partial,
        const float* __restrict__ fc_w,   const float* __restrict__ fc_b,
        const float* __restrict__ xyz_w,  const float* __restrict__ xyz_b,
        const float* __restrict__ wpqr_w, const float* __restrict__ wpqr_b,
        float* __restrict__ out) {
    int e = blockIdx.x;
    int t = threadIdx.x;
    int a0 = ei[e], a1 = ei[N_EDGES + e];
    int pi = min(a0, a1), pj = max(a0, a1);
    int rank = pi * 8 - ((pi * (pi + 1)) >> 1) + pj;
    __shared__ float pl[CO];
    if (t < CO) {
        float s = 0.f;
#pragma unroll
        for (int rt = 0; rt < 16; ++rt)
            s += partial[(rt * 36 + rank) * 64 + t];
        pl[t] = s * (1.f / 4096.f);
    }
    __syncthreads();

    float s[6] = {0.f, 0.f, 0.f, 0.f, 0.f, 0.f};
#pragma unroll
    for (int ff = 0; ff < 4; ++ff) {
        int f = ff * 256 + t;
        const float* wr = fc_w + f * CO;
        float d = fc_b[f];
#pragma unroll
        for (int c = 0; c < CO; ++c) d = fmaf(pl[c], wr[c], d);
        d = fmaxf(d, 0.f);
#pragma unroll
        for (int r = 0; r < 3; ++r) {
            s[r]     = fmaf(d, xyz_w[r * FEAT + f],  s[r]);
            s[3 + r] = fmaf(d, wpqr_w[r * FEAT + f], s[3 + r]);
        }
    }
#pragma unroll
    for (int r = 0; r < 6; ++r)
#pragma unroll
        for (int off = 32; off > 0; off >>= 1)
            s[r] += __shfl_down(s[r], off, 64);

    __shared__ float red[4][6];
    if ((t & 63) == 0) {
#pragma unroll
        for (int r = 0; r < 6; ++r) red[t >> 6][r] = s[r];
    }
    __syncthreads();
    if (t < 6) {
        float v = red[0][t] + red[1][t] + red[2][t] + red[3][t];
        v += (t < 3) ? xyz_b[t] : wpqr_b[t - 3];
        out[48 + e * 6 + t] = v;
        if (e < 8) out[e * 6 + t] = v;
    }
}

// ---------------------------------------------------------------------------
extern "C" void kernel_launch(void* const* d_in, const int* in_sizes, int n_in,
                              void* d_out, int out_size, void* d_ws, size_t ws_size,
                              hipStream_t stream) {
    const float* x        = (const float*)d_in[0];
    const int*   ei       = (const int*)d_in[1];
    const float* conv1_w  = (const float*)d_in[2];
    const float* bn_gamma = (const float*)d_in[3];
    const float* bn_beta  = (const float*)d_in[4];
    const float* bn_mean  = (const float*)d_in[5];
    const float* bn_var   = (const float*)d_in[6];
    const float* fc_w     = (const float*)d_in[7];
    const float* fc_b     = (const float*)d_in[8];
    const float* xyz_w    = (const float*)d_in[9];
    const float* xyz_b    = (const float*)d_in[10];
    const float* wpqr_w   = (const float*)d_in[11];
    const float* wpqr_b   = (const float*)d_in[12];
    float* out = (float*)d_out;

    char* ws = (char*)d_ws;
    float*          partial = (float*)(ws + OFF_PARTIAL);
    unsigned*       xpad    = (unsigned*)(ws + OFF_XPAD);
    unsigned short* wb2     = (unsigned short*)(ws + OFF_WB);
    unsigned short* A2      = (unsigned short*)(ws + OFF_A);
    unsigned short* B2      = (unsigned short*)(ws + OFF_B);

    int img_work = 8 * 3 * 262 * XROW;
    prep_kernel<<<(img_work + 255) / 256, 256, 0, stream>>>(
        x, conv1_w, bn_gamma, bn_var, xpad, wb2);
    conv_kernel<<<1024, 1024, 0, stream>>>(xpad, wb2, bn_gamma, bn_beta,
                                           bn_mean, bn_var, A2, B2);
    pool_kernel<<<1024, 256, 0, stream>>>(A2, B2, partial);
    head_kernel<<<64, 256, 0, stream>>>(ei, partial, fc_w, fc_b,
                                        xyz_w, xyz_b, wpqr_w, wpqr_b, out);
}